// Round 8
// baseline (114.849 us; speedup 1.0000x reference)
//
#include <hip/hip_runtime.h>
#include <math.h>

#define EPSV 1e-12f

typedef __attribute__((ext_vector_type(8))) short short8;
typedef __attribute__((ext_vector_type(4))) float f32x4;

constexpr int MT    = 10;            // M-tiles of 16 -> K_PAD = 160 class rows
constexpr int K_PAD = MT * 16;
constexpr int CPB   = 64;            // channels per block
constexpr int CHUNK = 128;           // pixels per staged chunk (4 ksteps)
constexpr int PBPX  = 512;           // pixels per pixel-block
constexpr int NCHK  = PBPX / CHUNK;  // 4 chunks
constexpr int NPB   = 256;           // pixel-blocks (131072/512)
constexpr int THR   = 512;           // 8 waves
constexpr int LROW  = 136;           // LDS B-row stride in shorts (16B-aligned rows)

__device__ __forceinline__ unsigned short f2bf(float f) {
    unsigned u = __builtin_bit_cast(unsigned, f);
    return (unsigned short)((u + 0x7FFFu + ((u >> 16) & 1u)) >> 16);  // RNE
}

// ---------------------------------------------------------------------------
// protomm: segment-sum via one-hot MFMA GEMM.
// Wave w: ct = w&3 (channel tile), par = w>>2; owns m in {par,par+2,..,par+8}
// with FULL K per wave -> complete accumulators, no k-half LDS reduce, no
// fscr. LDS = 36 KB -> 4 blocks/CU (32 waves/CU TLP hides HBM latency).
// ---------------------------------------------------------------------------
__global__ __launch_bounds__(THR, 8) void protomm_kernel(
    const float* __restrict__ feat,     // [B,C,HW]
    const int*   __restrict__ labels,   // [B,HW]
    const int*   __restrict__ ign_p,
    float*       __restrict__ partial,  // [NPB][K_PAD][C]
    float*       __restrict__ vmask,    // [K_PAD] pre-zeroed
    int C, int HW)
{
    __shared__ unsigned short Bf[2][CPB * LROW];   // 34.8 KB
    __shared__ int   labL[2][CHUNK];               // 1 KB
    __shared__ unsigned char pres[K_PAD];

    const int tid   = threadIdx.x;
    const int w     = tid >> 6;
    const int l     = tid & 63;
    const int ct    = w & 3;        // channel tile (16 ch)
    const int par   = w >> 2;       // m parity
    const int rowid = l & 15;
    const int g     = l >> 4;

    const int bid = blockIdx.x;
    const int cg  = bid & 3;        // channel group (64 ch)
    const int pb  = bid >> 2;       // pixel strip 0..255
    const int b   = pb >> 5;        // image (32 strips/image)
    const int px0 = (pb & 31) * PBPX;
    const int ig  = *ign_p;

    const int qq  = tid & 31;
    const int chp = tid >> 5;       // 0..15
    const float* fb = feat + ((size_t)(b * C + cg * CPB + chp)) * HW + px0 + 4 * qq;
    const int*   lb = labels + (size_t)b * HW + px0;

    if (cg == 0)
        for (int i = tid; i < K_PAD; i += THR) pres[i] = 0;

    f32x4 acc[5];
    #pragma unroll
    for (int j = 0; j < 5; ++j) acc[j] = (f32x4){0.f, 0.f, 0.f, 0.f};

    float4 pf0, pf1, pf2, pf3;
    int4   plab;
    auto issue = [&](int ck) {
        const float* p = fb + ck * CHUNK;
        pf0 = *reinterpret_cast<const float4*>(p);
        pf1 = *reinterpret_cast<const float4*>(p + (size_t)16 * HW);
        pf2 = *reinterpret_cast<const float4*>(p + (size_t)32 * HW);
        pf3 = *reinterpret_cast<const float4*>(p + (size_t)48 * HW);
        if (tid < 32)
            plab = *reinterpret_cast<const int4*>(lb + ck * CHUNK + 4 * tid);
    };
    auto commit = [&](int buf) {
        float4 v[4] = {pf0, pf1, pf2, pf3};
        #pragma unroll
        for (int i = 0; i < 4; ++i) {
            unsigned* dst = reinterpret_cast<unsigned*>(
                &Bf[buf][(chp + 16 * i) * LROW + 4 * qq]);
            dst[0] = (unsigned)f2bf(v[i].x) | ((unsigned)f2bf(v[i].y) << 16);
            dst[1] = (unsigned)f2bf(v[i].z) | ((unsigned)f2bf(v[i].w) << 16);
        }
        if (tid < 32) {
            int4 lv = plab;
            lv.x = (lv.x == ig) ? 0 : lv.x;
            lv.y = (lv.y == ig) ? 0 : lv.y;
            lv.z = (lv.z == ig) ? 0 : lv.z;
            lv.w = (lv.w == ig) ? 0 : lv.w;
            *reinterpret_cast<int4*>(&labL[buf][4 * tid]) = lv;
        }
    };

    issue(0);

    for (int ck = 0; ck < NCHK; ++ck) {
        const int cur = ck & 1;
        commit(cur);                        // vmcnt wait for chunk ck loads
        if (ck + 1 < NCHK) issue(ck + 1);   // next chunk in flight under MFMA
        __syncthreads();

        if (cg == 0 && tid < CHUNK) {       // presence bytes (races benign)
            int la = labL[cur][tid];
            if ((unsigned)la < (unsigned)K_PAD) pres[la] = 1;
        }

        #pragma unroll
        for (int ks = 0; ks < CHUNK / 32; ++ks) {
            const int4 lA = *reinterpret_cast<const int4*>(&labL[cur][ks * 32 + g * 8]);
            const int4 lB = *reinterpret_cast<const int4*>(&labL[cur][ks * 32 + g * 8 + 4]);
            const short8 bfrag = *reinterpret_cast<const short8*>(
                &Bf[cur][(ct * 16 + rowid) * LROW + ks * 32 + g * 8]);
            #pragma unroll
            for (int j = 0; j < 5; ++j) {
                const int tgt = (par + 2 * j) * 16 + rowid;
                unsigned w0 = (lA.x == tgt ? 0x3F80u : 0u) | (lA.y == tgt ? 0x3F800000u : 0u);
                unsigned w1 = (lA.z == tgt ? 0x3F80u : 0u) | (lA.w == tgt ? 0x3F800000u : 0u);
                unsigned w2 = (lB.x == tgt ? 0x3F80u : 0u) | (lB.y == tgt ? 0x3F800000u : 0u);
                unsigned w3 = (lB.z == tgt ? 0x3F80u : 0u) | (lB.w == tgt ? 0x3F800000u : 0u);
                uint4 aw = make_uint4(w0, w1, w2, w3);
                short8 afrag = __builtin_bit_cast(short8, aw);
                acc[j] = __builtin_amdgcn_mfma_f32_16x16x32_bf16(afrag, bfrag, acc[j], 0, 0, 0);
            }
        }
    }

    // flush: each wave owns complete sums for its (m-set, ct) -> plain stores
    {
        float* dst = partial + (size_t)pb * K_PAD * C + cg * CPB + ct * 16 + rowid;
        #pragma unroll
        for (int j = 0; j < 5; ++j) {
            const int m = par + 2 * j;
            #pragma unroll
            for (int r = 0; r < 4; ++r) {
                const int cls = m * 16 + g * 4 + r;
                dst[(size_t)cls * C] = acc[j][r];
            }
        }
    }
    if (cg == 0) {
        __syncthreads();                    // all pres writes visible
        for (int i = tid; i < K_PAD; i += THR)
            if (pres[i]) vmask[i] = 1.0f;
    }
}

// ---------------------------------------------------------------------------
// tail: block k. Phase 1: float4 reduce of partial row k over NPB=256 slots
// (8 chains) + L2-normalize (count-divide cancels). Phase 2: text sweep,
// float4 loads, fused text-norm + online logsumexp. Ticket finalize.
// ---------------------------------------------------------------------------
__global__ __launch_bounds__(256) void tail_kernel(
    const float* __restrict__ partial,    // [NPB][K_PAD][C]
    const float* __restrict__ text,       // [K][C]
    const float* __restrict__ vmask,      // [K_PAD]
    float* __restrict__ loss_acc,
    unsigned int* __restrict__ ticket,
    float* __restrict__ out,
    int K, int C, int nblocks)
{
    __shared__ float ph[256];
    __shared__ float scr[4][260];
    __shared__ float vm[K_PAD];
    __shared__ float red[5];
    __shared__ float wred[12];
    __shared__ unsigned int lastflag;

    const int k    = blockIdx.x;
    const int tid  = threadIdx.x;
    const int wid  = tid >> 6;
    const int lane = tid & 63;

    if (tid < K_PAD) vm[tid] = vmask[tid];
    __syncthreads();
    const bool valid = (vm[k] > 0.f);

    float contrib = 0.f;
    if (valid) {
        // phase 1: thread (sg, cq); slots s === sg (mod 4), 8 independent chains
        const int cq = tid & 63;
        const int sg = tid >> 6;
        const size_t gs = (size_t)K_PAD * C;
        const float* pbase = partial + (size_t)k * C + 4 * cq;
        float4 a0 = {0,0,0,0}, a1 = {0,0,0,0}, a2 = {0,0,0,0}, a3 = {0,0,0,0};
        float4 a4 = {0,0,0,0}, a5 = {0,0,0,0}, a6 = {0,0,0,0}, a7 = {0,0,0,0};
        for (int o = 0; o < NPB; o += 32) {
            a0 += *(const float4*)(pbase + (size_t)(o + sg +  0) * gs);
            a1 += *(const float4*)(pbase + (size_t)(o + sg +  4) * gs);
            a2 += *(const float4*)(pbase + (size_t)(o + sg +  8) * gs);
            a3 += *(const float4*)(pbase + (size_t)(o + sg + 12) * gs);
            a4 += *(const float4*)(pbase + (size_t)(o + sg + 16) * gs);
            a5 += *(const float4*)(pbase + (size_t)(o + sg + 20) * gs);
            a6 += *(const float4*)(pbase + (size_t)(o + sg + 24) * gs);
            a7 += *(const float4*)(pbase + (size_t)(o + sg + 28) * gs);
        }
        float4 asum = (((a0 + a1) + (a2 + a3)) + ((a4 + a5) + (a6 + a7)));
        *(float4*)&scr[sg][4 * cq] = asum;
        __syncthreads();
        float val = scr[0][tid] + scr[1][tid] + scr[2][tid] + scr[3][tid];

        float v = val * val;
        #pragma unroll
        for (int o = 32; o > 0; o >>= 1) v += __shfl_down(v, o);
        if (lane == 0) red[wid] = v;
        __syncthreads();
        if (tid == 0) {
            float s = red[0] + red[1] + red[2] + red[3];
            red[4] = 1.0f / fmaxf(sqrtf(s), EPSV);
        }
        __syncthreads();
        ph[tid] = val * red[4];
        __syncthreads();

        // phase 2: 10 groups x (4 waves x 4 rows); float4 loads, fused norm
        const float4 pv = *(const float4*)&ph[4 * lane];
        float m = -INFINITY, s = 0.f, skk = 0.f;
        #pragma unroll 1
        for (int gq = 0; gq < K_PAD / 16; ++gq) {
            const int j0 = gq * 16 + wid * 4;
            const float4* t0 = (const float4*)(text + (size_t)(j0 + 0 < K ? j0 + 0 : 0) * C);
            const float4* t1 = (const float4*)(text + (size_t)(j0 + 1 < K ? j0 + 1 : 0) * C);
            const float4* t2 = (const float4*)(text + (size_t)(j0 + 2 < K ? j0 + 2 : 0) * C);
            const float4* t3 = (const float4*)(text + (size_t)(j0 + 3 < K ? j0 + 3 : 0) * C);
            float4 x0 = t0[lane], x1 = t1[lane], x2 = t2[lane], x3 = t3[lane];
            float d0 = pv.x*x0.x + pv.y*x0.y + pv.z*x0.z + pv.w*x0.w;
            float q0 = x0.x*x0.x + x0.y*x0.y + x0.z*x0.z + x0.w*x0.w;
            float d1 = pv.x*x1.x + pv.y*x1.y + pv.z*x1.z + pv.w*x1.w;
            float q1 = x1.x*x1.x + x1.y*x1.y + x1.z*x1.z + x1.w*x1.w;
            float d2 = pv.x*x2.x + pv.y*x2.y + pv.z*x2.z + pv.w*x2.w;
            float q2 = x2.x*x2.x + x2.y*x2.y + x2.z*x2.z + x2.w*x2.w;
            float d3 = pv.x*x3.x + pv.y*x3.y + pv.z*x3.z + pv.w*x3.w;
            float q3 = x3.x*x3.x + x3.y*x3.y + x3.z*x3.z + x3.w*x3.w;
            #pragma unroll
            for (int o = 32; o > 0; o >>= 1) {
                d0 += __shfl_down(d0, o); d1 += __shfl_down(d1, o);
                d2 += __shfl_down(d2, o); d3 += __shfl_down(d3, o);
                q0 += __shfl_down(q0, o); q1 += __shfl_down(q1, o);
                q2 += __shfl_down(q2, o); q3 += __shfl_down(q3, o);
            }
            if (lane == 0) {
                float dd[4] = {d0, d1, d2, d3};
                float qq[4] = {q0, q1, q2, q3};
                #pragma unroll
                for (int r = 0; r < 4; ++r) {
                    int j = j0 + r;
                    float vmj = vm[j];
                    float sim = dd[r] * (10.0f / fmaxf(sqrtf(qq[r]), EPSV));
                    float ms  = vmj * sim - (1.f - vmj) * 1e9f;
                    if (j == k) skk = ms;
                    if (ms > m) { s = s * __expf(m - ms) + 1.f; m = ms; }
                    else        { s += __expf(ms - m); }
                }
            }
        }
        if (lane == 0) { wred[wid*3+0] = m; wred[wid*3+1] = s; wred[wid*3+2] = skk; }
        __syncthreads();
        if (tid == 0) {
            float M = fmaxf(fmaxf(wred[0], wred[3]), fmaxf(wred[6], wred[9]));
            float S = 0.f, SKK = 0.f;
            #pragma unroll
            for (int ww = 0; ww < 4; ++ww) {
                S   += wred[ww*3+1] * __expf(wred[ww*3+0] - M);
                SKK += wred[ww*3+2];
            }
            contrib = M + logf(S) - SKK;      // -logp[k][k]
        }
    }

    // ticket: loss atomic, fence, last block finalizes
    if (tid == 0) {
        if (valid) atomicAdd(loss_acc, contrib);
        __threadfence();
        unsigned old = atomicAdd(ticket, 1u);
        lastflag = (old == (unsigned)(nblocks - 1)) ? 1u : 0u;
    }
    __syncthreads();
    if (lastflag) {
        float v = (tid < K_PAD) ? vm[tid] : 0.f;
        #pragma unroll
        for (int o = 32; o > 0; o >>= 1) v += __shfl_down(v, o);
        if (lane == 0) red[wid] = v;
        __syncthreads();
        if (tid == 0) {
            float nv = red[0] + red[1] + red[2] + red[3];
            float total = atomicAdd(loss_acc, 0.0f);   // device-scope read
            out[0] = (nv > 1.f) ? total / fmaxf(nv, 1.f) : 0.f;
        }
    }
}

extern "C" void kernel_launch(void* const* d_in, const int* in_sizes, int n_in,
                              void* d_out, int out_size, void* d_ws, size_t ws_size,
                              hipStream_t stream) {
    const float* feat   = (const float*)d_in[0];
    const int*   labels = (const int*)d_in[1];
    const float* text   = (const float*)d_in[2];
    const int*   ign    = (const int*)d_in[3];

    const int B  = 8;
    const int N  = in_sizes[1];          // 131072
    const int HW = N / B;                // 16384
    const int C  = in_sizes[0] / N;      // 256
    const int K  = in_sizes[2] / C;      // 150

    // workspace: partial [NPB][K_PAD][C] (~42 MB, fully overwritten) | vmask | acc | ticket
    float*        partial  = (float*)d_ws;
    float*        vmask    = partial + (size_t)NPB * K_PAD * C;
    float*        loss_acc = vmask + K_PAD;
    unsigned int* ticket   = (unsigned int*)(loss_acc + 1);

    hipMemsetAsync(vmask, 0, (K_PAD + 2) * sizeof(float), stream);

    protomm_kernel<<<NPB * 4, THR, 0, stream>>>(
        feat, labels, ign, partial, vmask, C, HW);

    tail_kernel<<<K, 256, 0, stream>>>(
        partial, text, vmask, loss_acc, ticket, (float*)d_out, K, C, K);
}

// Round 9
// 80.805 us; speedup vs baseline: 1.4213x; 1.4213x over previous
//
#include <hip/hip_runtime.h>
#include <math.h>

#define EPSV 1e-12f

typedef __attribute__((ext_vector_type(8))) short short8;
typedef __attribute__((ext_vector_type(4))) float f32x4;

constexpr int MT    = 10;            // M-tiles of 16 -> K_PAD = 160 class rows
constexpr int K_PAD = MT * 16;
constexpr int PBPX  = 512;           // pixels per strip
constexpr int NKS   = PBPX / 32;     // 16 ksteps per strip
constexpr int NPB   = 256;           // strips (131072/512)
constexpr int THR   = 512;           // 8 waves = 8 channel tiles of 16

__global__ __launch_bounds__(THR, 4) void protomm_kernel(
    const float* __restrict__ feat,     // [B,C,HW]
    const int*   __restrict__ labels,   // [B,HW]
    const int*   __restrict__ ign_p,
    float*       __restrict__ partial,  // [NPB][K_PAD][C]
    float*       __restrict__ vmask,    // [K_PAD] pre-zeroed
    int C, int HW)
{
    __shared__ int   labL[PBPX];            // 2 KB
    __shared__ float ftile[16][132];        // 8.25 KB flush staging
    __shared__ unsigned char pres[K_PAD];

    const int tid   = threadIdx.x;
    const int ct    = tid >> 6;         // wave id = channel tile (16 ch)
    const int l     = tid & 63;
    const int rowid = l & 15;
    const int g     = l >> 4;

    const int bid = blockIdx.x;
    const int cg  = bid & 1;            // 128-channel group
    const int pb  = bid >> 1;           // strip 0..255
    const int b   = pb >> 5;            // image (32 strips per image)
    const int px0 = (pb & 31) * PBPX;
    const int ig  = *ign_p;

    // labels once per block (single barrier in whole kernel body)
    if (cg == 0)
        for (int i = tid; i < K_PAD; i += THR) pres[i] = 0;
    {
        int lv = labels[(size_t)b * HW + px0 + tid];
        labL[tid] = (lv == ig) ? 0 : lv;
    }
    __syncthreads();
    if (cg == 0) {
        int lv = labL[tid];
        if ((unsigned)lv < (unsigned)K_PAD) pres[lv] = 1;   // same-value races ok
    }

    // per-lane B source: channel row (ct*16+rowid), pixel phase g*8
    const float* bbase = feat
        + ((size_t)(b * C + cg * 128 + ct * 16 + rowid)) * HW + px0 + g * 8;

    f32x4 acc[MT];
    #pragma unroll
    for (int m = 0; m < MT; ++m) acc[m] = (f32x4){0.f, 0.f, 0.f, 0.f};

    // 2-stage named-register pipeline (no runtime-indexed arrays)
    float4 xa0, xa1, xb0, xb1;
    auto LOADA = [&](int ks) {
        const float* p = bbase + ks * 32;
        xa0 = *reinterpret_cast<const float4*>(p);
        xa1 = *reinterpret_cast<const float4*>(p + 4);
    };
    auto LOADB = [&](int ks) {
        const float* p = bbase + ks * 32;
        xb0 = *reinterpret_cast<const float4*>(p);
        xb1 = *reinterpret_cast<const float4*>(p + 4);
    };
    auto CONSUME = [&](int ks, float4 x0, float4 x1) {
        unsigned w0, w1, w2, w3;
        asm("v_cvt_pk_bf16_f32 %0, %1, %2" : "=v"(w0) : "v"(x0.x), "v"(x0.y));
        asm("v_cvt_pk_bf16_f32 %0, %1, %2" : "=v"(w1) : "v"(x0.z), "v"(x0.w));
        asm("v_cvt_pk_bf16_f32 %0, %1, %2" : "=v"(w2) : "v"(x1.x), "v"(x1.y));
        asm("v_cvt_pk_bf16_f32 %0, %1, %2" : "=v"(w3) : "v"(x1.z), "v"(x1.w));
        uint4 bw = make_uint4(w0, w1, w2, w3);
        short8 bfrag = __builtin_bit_cast(short8, bw);
        const int4 lA = *reinterpret_cast<const int4*>(&labL[ks * 32 + g * 8]);
        const int4 lB = *reinterpret_cast<const int4*>(&labL[ks * 32 + g * 8 + 4]);
        #pragma unroll
        for (int m = 0; m < MT; ++m) {
            const int tgt = m * 16 + rowid;
            unsigned a0 = (lA.x == tgt ? 0x3F80u : 0u) | (lA.y == tgt ? 0x3F800000u : 0u);
            unsigned a1 = (lA.z == tgt ? 0x3F80u : 0u) | (lA.w == tgt ? 0x3F800000u : 0u);
            unsigned a2 = (lB.x == tgt ? 0x3F80u : 0u) | (lB.y == tgt ? 0x3F800000u : 0u);
            unsigned a3 = (lB.z == tgt ? 0x3F80u : 0u) | (lB.w == tgt ? 0x3F800000u : 0u);
            uint4 aw = make_uint4(a0, a1, a2, a3);
            short8 afrag = __builtin_bit_cast(short8, aw);
            acc[m] = __builtin_amdgcn_mfma_f32_16x16x32_bf16(afrag, bfrag, acc[m], 0, 0, 0);
        }
    };

    LOADA(0);
    LOADB(1);
    #pragma unroll 1
    for (int ks = 0; ks < NKS; ks += 2) {
        CONSUME(ks, xa0, xa1);
        if (ks + 2 < NKS) LOADA(ks + 2);
        CONSUME(ks + 1, xb0, xb1);
        if (ks + 3 < NKS) LOADB(ks + 3);
    }

    // flush: stage each 16x128 m-tile in LDS, store 512B-contiguous rows
    __syncthreads();
    #pragma unroll
    for (int m = 0; m < MT; ++m) {
        #pragma unroll
        for (int r = 0; r < 4; ++r)
            ftile[g * 4 + r][ct * 16 + rowid] = acc[m][r];
        __syncthreads();
        {
            const int row = tid >> 5, cq = tid & 31;
            float4 v = *reinterpret_cast<const float4*>(&ftile[row][4 * cq]);
            *reinterpret_cast<float4*>(
                partial + (size_t)pb * K_PAD * C + (size_t)(m * 16 + row) * C
                        + cg * 128 + 4 * cq) = v;
        }
        __syncthreads();
    }

    if (cg == 0)
        for (int i = tid; i < K_PAD; i += THR)
            if (pres[i]) vmask[i] = 1.0f;
}

// ---------------------------------------------------------------------------
// tail: block k. Phase 1: float4 reduce of partial row k over NPB=256 slots
// (8 chains) + L2-normalize (count-divide cancels). Phase 2: text sweep,
// float4 loads, fused text-norm + online logsumexp. Ticket finalize.
// ---------------------------------------------------------------------------
__global__ __launch_bounds__(256) void tail_kernel(
    const float* __restrict__ partial,    // [NPB][K_PAD][C]
    const float* __restrict__ text,       // [K][C]
    const float* __restrict__ vmask,      // [K_PAD]
    float* __restrict__ loss_acc,
    unsigned int* __restrict__ ticket,
    float* __restrict__ out,
    int K, int C, int nblocks)
{
    __shared__ float ph[256];
    __shared__ float scr[4][260];
    __shared__ float vm[K_PAD];
    __shared__ float red[5];
    __shared__ float wred[12];
    __shared__ unsigned int lastflag;

    const int k    = blockIdx.x;
    const int tid  = threadIdx.x;
    const int wid  = tid >> 6;
    const int lane = tid & 63;

    if (tid < K_PAD) vm[tid] = vmask[tid];
    __syncthreads();
    const bool valid = (vm[k] > 0.f);

    float contrib = 0.f;
    if (valid) {
        // phase 1: thread (sg, cq); slots s === sg (mod 4), 8 independent chains
        const int cq = tid & 63;
        const int sg = tid >> 6;
        const size_t gs = (size_t)K_PAD * C;
        const float* pbase = partial + (size_t)k * C + 4 * cq;
        float4 a0 = {0,0,0,0}, a1 = {0,0,0,0}, a2 = {0,0,0,0}, a3 = {0,0,0,0};
        float4 a4 = {0,0,0,0}, a5 = {0,0,0,0}, a6 = {0,0,0,0}, a7 = {0,0,0,0};
        for (int o = 0; o < NPB; o += 32) {
            a0 += *(const float4*)(pbase + (size_t)(o + sg +  0) * gs);
            a1 += *(const float4*)(pbase + (size_t)(o + sg +  4) * gs);
            a2 += *(const float4*)(pbase + (size_t)(o + sg +  8) * gs);
            a3 += *(const float4*)(pbase + (size_t)(o + sg + 12) * gs);
            a4 += *(const float4*)(pbase + (size_t)(o + sg + 16) * gs);
            a5 += *(const float4*)(pbase + (size_t)(o + sg + 20) * gs);
            a6 += *(const float4*)(pbase + (size_t)(o + sg + 24) * gs);
            a7 += *(const float4*)(pbase + (size_t)(o + sg + 28) * gs);
        }
        float4 asum = (((a0 + a1) + (a2 + a3)) + ((a4 + a5) + (a6 + a7)));
        *(float4*)&scr[sg][4 * cq] = asum;
        __syncthreads();
        float val = scr[0][tid] + scr[1][tid] + scr[2][tid] + scr[3][tid];

        float v = val * val;
        #pragma unroll
        for (int o = 32; o > 0; o >>= 1) v += __shfl_down(v, o);
        if (lane == 0) red[wid] = v;
        __syncthreads();
        if (tid == 0) {
            float s = red[0] + red[1] + red[2] + red[3];
            red[4] = 1.0f / fmaxf(sqrtf(s), EPSV);
        }
        __syncthreads();
        ph[tid] = val * red[4];
        __syncthreads();

        // phase 2: 10 groups x (4 waves x 4 rows); float4 loads, fused norm
        const float4 pv = *(const float4*)&ph[4 * lane];
        float m = -INFINITY, s = 0.f, skk = 0.f;
        #pragma unroll 1
        for (int gq = 0; gq < K_PAD / 16; ++gq) {
            const int j0 = gq * 16 + wid * 4;
            const float4* t0 = (const float4*)(text + (size_t)(j0 + 0 < K ? j0 + 0 : 0) * C);
            const float4* t1 = (const float4*)(text + (size_t)(j0 + 1 < K ? j0 + 1 : 0) * C);
            const float4* t2 = (const float4*)(text + (size_t)(j0 + 2 < K ? j0 + 2 : 0) * C);
            const float4* t3 = (const float4*)(text + (size_t)(j0 + 3 < K ? j0 + 3 : 0) * C);
            float4 x0 = t0[lane], x1 = t1[lane], x2 = t2[lane], x3 = t3[lane];
            float d0 = pv.x*x0.x + pv.y*x0.y + pv.z*x0.z + pv.w*x0.w;
            float q0 = x0.x*x0.x + x0.y*x0.y + x0.z*x0.z + x0.w*x0.w;
            float d1 = pv.x*x1.x + pv.y*x1.y + pv.z*x1.z + pv.w*x1.w;
            float q1 = x1.x*x1.x + x1.y*x1.y + x1.z*x1.z + x1.w*x1.w;
            float d2 = pv.x*x2.x + pv.y*x2.y + pv.z*x2.z + pv.w*x2.w;
            float q2 = x2.x*x2.x + x2.y*x2.y + x2.z*x2.z + x2.w*x2.w;
            float d3 = pv.x*x3.x + pv.y*x3.y + pv.z*x3.z + pv.w*x3.w;
            float q3 = x3.x*x3.x + x3.y*x3.y + x3.z*x3.z + x3.w*x3.w;
            #pragma unroll
            for (int o = 32; o > 0; o >>= 1) {
                d0 += __shfl_down(d0, o); d1 += __shfl_down(d1, o);
                d2 += __shfl_down(d2, o); d3 += __shfl_down(d3, o);
                q0 += __shfl_down(q0, o); q1 += __shfl_down(q1, o);
                q2 += __shfl_down(q2, o); q3 += __shfl_down(q3, o);
            }
            if (lane == 0) {
                float dd[4] = {d0, d1, d2, d3};
                float qq[4] = {q0, q1, q2, q3};
                #pragma unroll
                for (int r = 0; r < 4; ++r) {
                    int j = j0 + r;
                    float vmj = vm[j];
                    float sim = dd[r] * (10.0f / fmaxf(sqrtf(qq[r]), EPSV));
                    float ms  = vmj * sim - (1.f - vmj) * 1e9f;
                    if (j == k) skk = ms;
                    if (ms > m) { s = s * __expf(m - ms) + 1.f; m = ms; }
                    else        { s += __expf(ms - m); }
                }
            }
        }
        if (lane == 0) { wred[wid*3+0] = m; wred[wid*3+1] = s; wred[wid*3+2] = skk; }
        __syncthreads();
        if (tid == 0) {
            float M = fmaxf(fmaxf(wred[0], wred[3]), fmaxf(wred[6], wred[9]));
            float S = 0.f, SKK = 0.f;
            #pragma unroll
            for (int ww = 0; ww < 4; ++ww) {
                S   += wred[ww*3+1] * __expf(wred[ww*3+0] - M);
                SKK += wred[ww*3+2];
            }
            contrib = M + logf(S) - SKK;      // -logp[k][k]
        }
    }

    // ticket: loss atomic, fence, last block finalizes
    if (tid == 0) {
        if (valid) atomicAdd(loss_acc, contrib);
        __threadfence();
        unsigned old = atomicAdd(ticket, 1u);
        lastflag = (old == (unsigned)(nblocks - 1)) ? 1u : 0u;
    }
    __syncthreads();
    if (lastflag) {
        float v = (tid < K_PAD) ? vm[tid] : 0.f;
        #pragma unroll
        for (int o = 32; o > 0; o >>= 1) v += __shfl_down(v, o);
        if (lane == 0) red[wid] = v;
        __syncthreads();
        if (tid == 0) {
            float nv = red[0] + red[1] + red[2] + red[3];
            float total = atomicAdd(loss_acc, 0.0f);   // device-scope read
            out[0] = (nv > 1.f) ? total / fmaxf(nv, 1.f) : 0.f;
        }
    }
}

extern "C" void kernel_launch(void* const* d_in, const int* in_sizes, int n_in,
                              void* d_out, int out_size, void* d_ws, size_t ws_size,
                              hipStream_t stream) {
    const float* feat   = (const float*)d_in[0];
    const int*   labels = (const int*)d_in[1];
    const float* text   = (const float*)d_in[2];
    const int*   ign    = (const int*)d_in[3];

    const int B  = 8;
    const int N  = in_sizes[1];          // 131072
    const int HW = N / B;                // 16384
    const int C  = in_sizes[0] / N;      // 256
    const int K  = in_sizes[2] / C;      // 150

    // workspace: partial [NPB][K_PAD][C] (~42 MB, fully overwritten) | vmask | acc | ticket
    float*        partial  = (float*)d_ws;
    float*        vmask    = partial + (size_t)NPB * K_PAD * C;
    float*        loss_acc = vmask + K_PAD;
    unsigned int* ticket   = (unsigned int*)(loss_acc + 1);

    hipMemsetAsync(vmask, 0, (K_PAD + 2) * sizeof(float), stream);

    protomm_kernel<<<NPB * 2, THR, 0, stream>>>(
        feat, labels, ign, partial, vmask, C, HW);

    tail_kernel<<<K, 256, 0, stream>>>(
        partial, text, vmask, loss_acc, ticket, (float*)d_out, K, C, K);
}